// Round 10
// baseline (79.290 us; speedup 1.0000x reference)
//
#include <hip/hip_runtime.h>

#define DSZ 128
#define NVOX 4194304.0f

__global__ void ncc_zero(float* out) { out[0] = 0.0f; }

__device__ __forceinline__ float4 f4add(const float4 a, const float4 b) {
    return make_float4(a.x + b.x, a.y + b.y, a.z + b.z, a.w + b.w);
}
__device__ __forceinline__ float4 f4sub(const float4 a, const float4 b) {
    return make_float4(a.x - b.x, a.y - b.y, a.z - b.z, a.w - b.w);
}

// Tile 16x × 16y × 16z, grid 1024, 4 blocks/CU (LDS 34.5 KB).
// A (global x-pass -> LDS) on waves 1-3, exactly 1 task/thread.
// B (y-pass coarsened x2 + ring-of-8 z-window) on waves 0-1.
// Quad-buffer: A stages round rnd+1's slot pair while B reads rnd's. 1 barrier/round.
__global__ __launch_bounds__(256, 4) void ncc_main(const float* __restrict__ Iin,
                                                   const float* __restrict__ Jin,
                                                   float* __restrict__ out)
{
    const int tx0 = blockIdx.x * 16;
    const int ty0 = blockIdx.y * 16;
    const int b   = blockIdx.z >> 3;
    const int tz0 = (blockIdx.z & 7) * 16;
    const int tid = threadIdx.x;

    const float* __restrict__ Ib = Iin + b * (DSZ * DSZ * DSZ);
    const float* __restrict__ Jb = Jin + b * (DSZ * DSZ * DSZ);

    // s4m: (sumI,sumJ,sumII,sumJJ) stride 17 f4; s1v: sumIJ stride 24 floats.
    __shared__ float4 s4m[4][24][17];   // 26112 B
    __shared__ float  s1v[4][24][24];   //  9216 B

    // ---- B mapping (waves 0-1): thread owns columns y = 2ys, 2ys+1 at x = lx
    const bool isB = (tid < 128);
    const int  lx  = tid & 15;
    const int  ys  = (tid >> 4) & 7;

    // ---- A mapping (waves 1-3): one task each
    const bool isA = (tid >= 64);
    const int  ta  = tid - 64;              // 0..191
    const int  pA  = (ta >= 96) ? 1 : 0;    // plane of the round
    const int  t2  = ta - 96 * pA;          // 0..95
    const int  rA  = t2 >> 2;               // 0..23 halo row
    const int  xgA = t2 & 3;                // group of 4 x-outputs
    const int  gyA = ty0 + rA - 4;
    const int  gxbA = tx0 + 4 * xgA - 4;
    const bool yokA = ((unsigned)gyA < (unsigned)DSZ);

    auto stageA = [&](const int rnd) {
        const int zp = tz0 + 2 * rnd + pA - 4;
        const bool ok = yokA && ((unsigned)zp < (unsigned)DSZ);
        const int zoff = (zp * DSZ + gyA) * DSZ;
        float vi[12], vj[12];
#pragma unroll
        for (int g = 0; g < 3; ++g) {
            const int gx = gxbA + 4 * g;
            float4 va = make_float4(0.f, 0.f, 0.f, 0.f);
            float4 vb = va;
            if (ok && (unsigned)gx < (unsigned)DSZ) {
                va = *(const float4*)(Ib + zoff + gx);
                vb = *(const float4*)(Jb + zoff + gx);
            }
            vi[4*g+0]=va.x; vi[4*g+1]=va.y; vi[4*g+2]=va.z; vi[4*g+3]=va.w;
            vj[4*g+0]=vb.x; vj[4*g+1]=vb.y; vj[4*g+2]=vb.z; vj[4*g+3]=vb.w;
        }
        float wI=0.f, wJ=0.f, wII=0.f, wJJ=0.f, wIJ=0.f;
#pragma unroll
        for (int k = 0; k < 9; ++k) {
            wI += vi[k]; wJ += vj[k];
            wII = fmaf(vi[k], vi[k], wII);
            wJJ = fmaf(vj[k], vj[k], wJJ);
            wIJ = fmaf(vi[k], vj[k], wIJ);
        }
        const int sl = (rnd & 1) * 2 + pA;
        float mIJ[4];
        s4m[sl][rA][4*xgA] = make_float4(wI, wJ, wII, wJJ);
        mIJ[0] = wIJ;
#pragma unroll
        for (int j = 1; j < 4; ++j) {
            const float ai = vi[8+j], aj = vj[8+j];
            const float di = vi[j-1], dj = vj[j-1];
            wI += ai - di; wJ += aj - dj;
            wII += fmaf(ai, ai, -di * di);
            wJJ += fmaf(aj, aj, -dj * dj);
            wIJ += fmaf(ai, aj, -di * dj);
            s4m[sl][rA][4*xgA + j] = make_float4(wI, wJ, wII, wJJ);
            mIJ[j] = wIJ;
        }
        *(float4*)&s1v[sl][rA][4*xgA] = make_float4(mIJ[0], mIJ[1], mIJ[2], mIJ[3]);
    };

    // ---- ring-of-8 z-window for the 2 owned columns (B-threads only live) ----
    float4 rAv4[8], rBv4[8];
    float  rAs1[8], rBs1[8];
#pragma unroll
    for (int i = 0; i < 8; ++i) {
        rAv4[i] = make_float4(0.f, 0.f, 0.f, 0.f); rBv4[i] = rAv4[i];
        rAs1[i] = 0.f; rBs1[i] = 0.f;
    }
    float4 zA4 = make_float4(0.f, 0.f, 0.f, 0.f), zB4 = zA4;
    float  zA1 = 0.f, zB1 = 0.f;
    float  acc = 0.f;

    auto emit_cc = [&](const float4& z4, const float z1) {
        const float inv = 1.0f / 729.0f;
        const float uI = z4.x * inv;
        const float uJ = z4.y * inv;
        const float cross = z1 - uJ * z4.x - uI * z4.y + uI * uJ * 729.0f;
        const float Ivar  = z4.z - 2.0f * uI * z4.x + uI * uI * 729.0f;
        const float Jvar  = z4.w - 2.0f * uJ * z4.y + uJ * uJ * 729.0f;
        acc += cross * cross / (Ivar * Jvar + 1e-5f);
    };

    // ---- prologue: stage round 0 ----
    if (isA) stageA(0);
    __syncthreads();

#pragma unroll 1                       // outer rolled: spill protection
    for (int mr = 0; mr < 3; ++mr) {
#pragma unroll
        for (int r4 = 0; r4 < 4; ++r4) {
            const int rnd = 4 * mr + r4;

            // A: stage next round's plane pair into the other slot pair
            // (overlaps B's reads of the current pair; waves 2-3 pure-A)
            if (rnd < 11 && isA) stageA(rnd + 1);

            // B: y-pass (2 columns from 10 rows) + ring z-update, both planes
            if (isB) {
#pragma unroll
                for (int p = 0; p < 2; ++p) {
                    const int sl = (r4 & 1) * 2 + p;
                    float4 c4 = make_float4(0.f, 0.f, 0.f, 0.f);
                    float  c1 = 0.f;
                    float4 r0v; float r0s;
#pragma unroll
                    for (int dy = 0; dy < 9; ++dy) {
                        const float4 t4 = s4m[sl][2*ys + dy][lx];
                        const float  t1 = s1v[sl][2*ys + dy][lx];
                        if (dy == 0) { r0v = t4; r0s = t1; }
                        c4 = f4add(c4, t4);
                        c1 += t1;
                    }
                    const float4 r9v = s4m[sl][2*ys + 9][lx];
                    const float  r9s = s1v[sl][2*ys + 9][lx];
                    const float4 d4 = f4add(f4sub(c4, r0v), r9v);   // col B sum
                    const float  d1 = c1 - r0s + r9s;

                    const int k = (2 * r4 + p) & 7;    // compile-time ring slot

                    // column A (y = ty0 + 2*ys)
                    zA4 = f4add(zA4, c4); zA1 += c1;
                    if (mr > 0) emit_cc(zA4, zA1);
                    zA4 = f4sub(zA4, rAv4[k]); zA1 -= rAs1[k];
                    rAv4[k] = c4; rAs1[k] = c1;

                    // column B (y = ty0 + 2*ys + 1)
                    zB4 = f4add(zB4, d4); zB1 += d1;
                    if (mr > 0) emit_cc(zB4, zB1);
                    zB4 = f4sub(zB4, rBv4[k]); zB1 -= rBs1[k];
                    rBv4[k] = d4; rBs1[k] = d1;
                }
            }
            __syncthreads();   // A(rnd+1) visible; B(rnd) done before A(rnd+2)
        }
    }

    // block reduction: wave shuffle then cross-wave via LDS
#pragma unroll
    for (int off = 32; off > 0; off >>= 1) acc += __shfl_down(acc, off);
    __shared__ float wpart[4];
    if ((tid & 63) == 0) wpart[tid >> 6] = acc;
    __syncthreads();
    if (tid == 0) {
        const float s = wpart[0] + wpart[1] + wpart[2] + wpart[3];
        atomicAdd(out, s * (-1.0f / NVOX));
    }
}

extern "C" void kernel_launch(void* const* d_in, const int* in_sizes, int n_in,
                              void* d_out, int out_size, void* d_ws, size_t ws_size,
                              hipStream_t stream)
{
    // setup_inputs order: d_in[0] = y_pred (J), d_in[1] = y_true (I)
    const float* J = (const float*)d_in[0];
    const float* I = (const float*)d_in[1];
    float* out = (float*)d_out;

    ncc_zero<<<dim3(1), dim3(1), 0, stream>>>(out);
    dim3 grid(DSZ / 16, DSZ / 16, 2 * (DSZ / 16));  // 8 x 8 x 16 = 1024 blocks
    ncc_main<<<grid, dim3(256), 0, stream>>>(I, J, out);
}

// Round 11
// 50.848 us; speedup vs baseline: 1.5594x; 1.5594x over previous
//
#include <hip/hip_runtime.h>
#include <hip/hip_fp16.h>

#define DSZ 128
#define NVOX 4194304.0f

__global__ void ncc_zero(float* out) { out[0] = 0.0f; }

__global__ __launch_bounds__(256, 3) void ncc_main(const float* __restrict__ Iin,
                                                   const float* __restrict__ Jin,
                                                   float* __restrict__ out)
{
    const int tx0 = blockIdx.x * 16;
    const int ty0 = blockIdx.y * 16;
    const int b   = blockIdx.z >> 3;
    const int tz0 = (blockIdx.z & 7) * 16;
    const int tid = threadIdx.x;
    const int lx  = tid & 15;       // Phase-B x
    const int ly  = tid >> 4;       // Phase-B y (0..15)

    const float* __restrict__ Ib = Iin + b * (DSZ * DSZ * DSZ);
    const float* __restrict__ Jb = Jin + b * (DSZ * DSZ * DSZ);

    // fp16-packed x-summed moments. Odd word stride (17) -> b32 gathers are
    // conflict-free (proven pattern); b128 gathers (7 conflict-cyc each,
    // layout-independent) are eliminated entirely.
    __shared__ __half2 hIJ[4][24][17];   // (sumI, sumJ)    6528 B
    __shared__ __half2 hQQ[4][24][17];   // (sumII, sumJJ)  6528 B
    __shared__ float   s1v[4][24][24];   // sumIJ (f32)     9216 B

    // ---- Phase-A static mapping (tid < 192: waves 0-2; all waves do B) ----
    const bool isA = (tid < 192);
    const int  pA  = (tid >= 96) ? 1 : 0;      // plane of the round
    const int  t2  = isA ? (tid - pA * 96) : 0;
    const int  rA  = t2 >> 2;                  // 0..23 halo row
    const int  xgA = t2 & 3;                   // group of 4 x-outputs
    const int  gyA = ty0 + rA - 4;
    const int  gxbA = tx0 + 4 * xgA - 4;
    const bool yokA = ((unsigned)gyA < (unsigned)DSZ);

    auto phaseA = [&](const int rnd) {
        const int zp = tz0 + 2 * rnd + pA - 4;
        const bool ok = yokA && ((unsigned)zp < (unsigned)DSZ);
        const int zoff = (zp * DSZ + gyA) * DSZ;
        float vi[12], vj[12];
#pragma unroll
        for (int g = 0; g < 3; ++g) {
            const int gx = gxbA + 4 * g;
            float4 va = make_float4(0.f, 0.f, 0.f, 0.f);
            float4 vb = va;
            if (ok && (unsigned)gx < (unsigned)DSZ) {
                va = *(const float4*)(Ib + zoff + gx);
                vb = *(const float4*)(Jb + zoff + gx);
            }
            vi[4*g+0]=va.x; vi[4*g+1]=va.y; vi[4*g+2]=va.z; vi[4*g+3]=va.w;
            vj[4*g+0]=vb.x; vj[4*g+1]=vb.y; vj[4*g+2]=vb.z; vj[4*g+3]=vb.w;
        }
        float wI=0.f, wJ=0.f, wII=0.f, wJJ=0.f, wIJ=0.f;
#pragma unroll
        for (int k = 0; k < 9; ++k) {
            wI += vi[k]; wJ += vj[k];
            wII = fmaf(vi[k], vi[k], wII);
            wJJ = fmaf(vj[k], vj[k], wJJ);
            wIJ = fmaf(vi[k], vj[k], wIJ);
        }
        const int sl = (rnd & 1) * 2 + pA;
        float mIJ[4];
        hIJ[sl][rA][4*xgA] = __floats2half2_rn(wI, wJ);
        hQQ[sl][rA][4*xgA] = __floats2half2_rn(wII, wJJ);
        mIJ[0] = wIJ;
#pragma unroll
        for (int j = 1; j < 4; ++j) {
            const float ai = vi[8+j], aj = vj[8+j];
            const float di = vi[j-1], dj = vj[j-1];
            wI += ai - di; wJ += aj - dj;
            wII += fmaf(ai, ai, -di * di);
            wJJ += fmaf(aj, aj, -dj * dj);
            wIJ += fmaf(ai, aj, -di * dj);
            hIJ[sl][rA][4*xgA + j] = __floats2half2_rn(wI, wJ);
            hQQ[sl][rA][4*xgA + j] = __floats2half2_rn(wII, wJJ);
            mIJ[j] = wIJ;
        }
        *(float4*)&s1v[sl][rA][4*xgA] = make_float4(mIJ[0], mIJ[1], mIJ[2], mIJ[3]);
    };

    // ---- 9-plane rolling z-window: shift registers (R3-proven, no spill) ----
    float rb0[9], rb1[9], rb2[9], rb3[9], rb4[9];
#pragma unroll
    for (int i = 0; i < 9; ++i) { rb0[i]=0.f; rb1[i]=0.f; rb2[i]=0.f; rb3[i]=0.f; rb4[i]=0.f; }
    float zs0=0.f, zs1=0.f, zs2=0.f, zs3=0.f, zs4=0.f;
    float acc = 0.f;

#pragma unroll 1                    // keep rolled: spill protection
    for (int rnd = 0; rnd < 12; ++rnd) {
        // ---- Phase A: direct-from-global x-pass -> fp16 LDS ----
        if (isA) phaseA(rnd);
        __syncthreads();            // quad-buffer => 1 barrier/round (R3-safe)

        // ---- Phase B: y-pass (27 conflict-free b32) + rolling z ----
#pragma unroll
        for (int p = 0; p < 2; ++p) {
            const int sl = (rnd & 1) * 2 + p;
            __half2 sIJ = hIJ[sl][ly][lx];
            __half2 sQQ = hQQ[sl][ly][lx];
            float   c1  = s1v[sl][ly][lx];
#pragma unroll
            for (int dy = 1; dy < 9; ++dy) {
                sIJ = __hadd2(sIJ, hIJ[sl][ly + dy][lx]);
                sQQ = __hadd2(sQQ, hQQ[sl][ly + dy][lx]);
                c1 += s1v[sl][ly + dy][lx];
            }
            const float2 ij = __half22float2(sIJ);
            const float2 qq = __half22float2(sQQ);

            zs0 += ij.x - rb0[0]; zs1 += ij.y - rb1[0]; zs2 += qq.x - rb2[0];
            zs3 += qq.y - rb3[0]; zs4 += c1 - rb4[0];
#pragma unroll
            for (int i = 0; i < 8; ++i) {
                rb0[i]=rb0[i+1]; rb1[i]=rb1[i+1]; rb2[i]=rb2[i+1];
                rb3[i]=rb3[i+1]; rb4[i]=rb4[i+1];
            }
            rb0[8]=ij.x; rb1[8]=ij.y; rb2[8]=qq.x; rb3[8]=qq.y; rb4[8]=c1;

            if (2 * rnd + p >= 8) {
                const float inv = 1.0f / 729.0f;
                const float uI = zs0 * inv;
                const float uJ = zs1 * inv;
                const float cross = zs4 - uJ * zs0 - uI * zs1 + uI * uJ * 729.0f;
                const float Ivar  = zs2 - 2.0f * uI * zs0 + uI * uI * 729.0f;
                const float Jvar  = zs3 - 2.0f * uJ * zs1 + uJ * uJ * 729.0f;
                acc += cross * cross / (Ivar * Jvar + 1e-5f);
            }
        }
    }

    // block reduction: wave shuffle then cross-wave via LDS
#pragma unroll
    for (int off = 32; off > 0; off >>= 1) acc += __shfl_down(acc, off);
    __shared__ float wpart[4];
    if ((tid & 63) == 0) wpart[tid >> 6] = acc;
    __syncthreads();
    if (tid == 0) {
        const float s = wpart[0] + wpart[1] + wpart[2] + wpart[3];
        atomicAdd(out, s * (-1.0f / NVOX));
    }
}

extern "C" void kernel_launch(void* const* d_in, const int* in_sizes, int n_in,
                              void* d_out, int out_size, void* d_ws, size_t ws_size,
                              hipStream_t stream)
{
    // setup_inputs order: d_in[0] = y_pred (J), d_in[1] = y_true (I)
    const float* J = (const float*)d_in[0];
    const float* I = (const float*)d_in[1];
    float* out = (float*)d_out;

    ncc_zero<<<dim3(1), dim3(1), 0, stream>>>(out);
    dim3 grid(DSZ / 16, DSZ / 16, 2 * (DSZ / 16));  // 8 x 8 x 16 = 1024 blocks
    ncc_main<<<grid, dim3(256), 0, stream>>>(I, J, out);
}